// Round 12
// baseline (98.779 us; speedup 1.0000x reference)
//
#include <hip/hip_runtime.h>
#include <float.h>

#define CHUNK 2048
#define SUB   1024   // cols per block
#define MBLK  256    // rows per block = 4 waves x 64 rows (two 32-row strips)

typedef __attribute__((ext_vector_type(8)))  short short8;
typedef __attribute__((ext_vector_type(16))) float f32x16;

// ---- bf16 split helpers (RN-even; inputs finite) ----
static __device__ __forceinline__ unsigned short f2bf(float f) {
    unsigned u = __float_as_uint(f);
    return (unsigned short)((u + 0x7FFFu + ((u >> 16) & 1u)) >> 16);
}
static __device__ __forceinline__ float bf2f(unsigned short s) {
    return __uint_as_float(((unsigned)s) << 16);
}

// ---- Pass 0: pack K=16 bf16 records ----
// A-record (p1 point):  [ph(3), pl(3), ph(3), pl(3), sp_hi, sp_lo, 1, 1]
// B-record (p2 point):  [uh(3), uh(3), ul(3), ul(3), 1, 1, sq_hi, sq_lo]
// Mutually transposable; dot(A_k,B_k) = sp + sq - 2 p.q with either side as
// the MFMA A-operand. Verified R5-R11 (absmax 0) in both orientations.
__global__ void pack_kernel(const float* __restrict__ p1,
                            const float* __restrict__ p2, int n1, int n2,
                            unsigned short* __restrict__ Arec,
                            unsigned short* __restrict__ Brec)
{
    int i = blockIdx.x * blockDim.x + threadIdx.x;
    if (i >= n1 + n2) return;
    const bool isA = (i < n1);
    const float* s = isA ? p1 : p2;
    const int j = isA ? i : i - n1;
    float x = s[3 * j + 0], y = s[3 * j + 1], z = s[3 * j + 2];

    unsigned short r[16];
    if (isA) {
        unsigned short hx = f2bf(x), hy = f2bf(y), hz = f2bf(z);
        unsigned short lx = f2bf(x - bf2f(hx)), ly = f2bf(y - bf2f(hy)),
                       lz = f2bf(z - bf2f(hz));
        float sp = fmaf(x, x, fmaf(y, y, z * z));
        unsigned short sh = f2bf(sp), sl = f2bf(sp - bf2f(sh));
        r[0]=hx; r[1]=hy; r[2]=hz;  r[3]=lx; r[4]=ly; r[5]=lz;
        r[6]=hx; r[7]=hy; r[8]=hz;  r[9]=lx; r[10]=ly; r[11]=lz;
        r[12]=sh; r[13]=sl; r[14]=0x3F80; r[15]=0x3F80;
        unsigned short* dst = Arec + (size_t)j * 16;
#pragma unroll
        for (int t = 0; t < 16; ++t) dst[t] = r[t];
    } else {
        float ux = -2.0f * x, uy = -2.0f * y, uz = -2.0f * z;
        unsigned short hx = f2bf(ux), hy = f2bf(uy), hz = f2bf(uz);
        unsigned short lx = f2bf(ux - bf2f(hx)), ly = f2bf(uy - bf2f(hy)),
                       lz = f2bf(uz - bf2f(hz));
        float sq = fmaf(x, x, fmaf(y, y, z * z));
        unsigned short sh = f2bf(sq), sl = f2bf(sq - bf2f(sh));
        r[0]=hx; r[1]=hy; r[2]=hz;  r[3]=hx; r[4]=hy; r[5]=hz;
        r[6]=lx; r[7]=ly; r[8]=lz;  r[9]=lx; r[10]=ly; r[11]=lz;
        r[12]=0x3F80; r[13]=0x3F80; r[14]=sh; r[15]=sl;
        unsigned short* dst = Brec + (size_t)j * 16;
#pragma unroll
        for (int t = 0; t < 16; ++t) dst[t] = r[t];
    }
}

// ---- rowmin tournament across 32 lanes (verified R6-R11, absmax 0) ----
static __device__ __forceinline__ float tourney16(float rm[16], int l31)
{
#pragma unroll
    for (int r = 0; r < 8; ++r) {
        float lo = fminf(rm[r],     __shfl_xor(rm[r],     16));
        float hi = fminf(rm[r + 8], __shfl_xor(rm[r + 8], 16));
        rm[r] = (l31 & 16) ? hi : lo;
    }
#pragma unroll
    for (int r = 0; r < 4; ++r) {
        float lo = fminf(rm[r],     __shfl_xor(rm[r],     8));
        float hi = fminf(rm[r + 4], __shfl_xor(rm[r + 4], 8));
        rm[r] = (l31 & 8) ? hi : lo;
    }
#pragma unroll
    for (int r = 0; r < 2; ++r) {
        float lo = fminf(rm[r],     __shfl_xor(rm[r],     4));
        float hi = fminf(rm[r + 2], __shfl_xor(rm[r + 2], 4));
        rm[r] = (l31 & 4) ? hi : lo;
    }
    {
        float lo = fminf(rm[0], __shfl_xor(rm[0], 2));
        float hi = fminf(rm[1], __shfl_xor(rm[1], 2));
        rm[0] = (l31 & 2) ? hi : lo;
    }
    return fminf(rm[0], __shfl_xor(rm[0], 1));
}

// ---- Pass 1: pure-rowmin MFMA kernel, both directions via blockIdx.z ----
// R12 theory: cross-round matrix (R8/R11 ~30us @524K loads+8w; R9 63us
// @262K loads+4w) says the wall is per-CU VMEM service time (~16-32 cyc per
// 1KB wave-load through the single TA/L1 port), and R9's load-halving was
// masked by its 4-wave latency regime. This round takes BOTH: 2 A-strips per
// wave (1 B load -> 2 MFMA + 32 fmin, 262K total loads) at LB(256,6) — the
// ~82-reg live set fits the 85-reg/wave budget of 6 waves/SIMD, unlike R9's
// self-inflicted LB(256,4).
// v_mfma_f32_32x32x16_bf16: A[m=lane&31][k=half*8+j], B[k=half*8+j][n=lane&31],
//   C/D: col=lane&31, row=(reg&3)+8*(reg>>2)+4*half.
__global__ __launch_bounds__(256, 6)
void chamfer_mfma(const unsigned short* __restrict__ Arec,
                  const unsigned short* __restrict__ Brec,
                  float* __restrict__ part2, float* __restrict__ part1,
                  int n1, int n2)
{
    const int dir = blockIdx.z;
    const unsigned short* __restrict__ Ap = dir ? Brec : Arec;
    const unsigned short* __restrict__ Bp = dir ? Arec : Brec;
    float* __restrict__ part = dir ? part1 : part2;
    const int rows_n = dir ? n2 : n1;
    const int cols_n = dir ? n1 : n2;

    const int tid  = threadIdx.x;
    const int g    = blockIdx.x;          // row group (256 rows of A-side)
    const int yb   = blockIdx.y;          // col sub-chunk (1024 cols of B-side)
    if (g * MBLK >= rows_n || yb * SUB >= cols_n) return;  // uniform

    const int lane = tid & 63;
    const int w    = tid >> 6;
    const int half = lane >> 5;
    const int l31  = lane & 31;

    // Two A fragments per wave: strips at +0 and +32 within the wave's 64 rows
    const int rA = g * MBLK + w * 64 + l31;
    short8 aA = *(const short8*)(Ap + (size_t)rA * 16 + half * 8);
    short8 aB = *(const short8*)(Ap + (size_t)(rA + 32) * 16 + half * 8);

    const unsigned short* bp =
        Bp + (size_t)(yb * SUB + l31) * 16 + half * 8;

    const f32x16 z16 = {0,0,0,0, 0,0,0,0, 0,0,0,0, 0,0,0,0};
    float rmA[16], rmB[16];
#pragma unroll
    for (int r = 0; r < 16; ++r) { rmA[r] = FLT_MAX; rmB[r] = FLT_MAX; }

    const int NT = SUB / 32;   // 32 tiles; 1 load -> 2 MFMA + 32 fmin
    for (int t = 0; t < NT; ++t) {
        short8 b = *(const short8*)(bp + (size_t)t * 512);
        f32x16 dA = __builtin_amdgcn_mfma_f32_32x32x16_bf16(aA, b, z16, 0, 0, 0);
#pragma unroll
        for (int r = 0; r < 16; ++r) rmA[r] = fminf(rmA[r], dA[r]);
        f32x16 dB = __builtin_amdgcn_mfma_f32_32x32x16_bf16(aB, b, z16, 0, 0, 0);
#pragma unroll
        for (int r = 0; r < 16; ++r) rmB[r] = fminf(rmB[r], dB[r]);
    }

    // ---- two tournaments, two plain stores per even lane ----
    float vA = tourney16(rmA, l31);
    float vB = tourney16(rmB, l31);
    if ((l31 & 1) == 0) {
        int r = (l31 >> 1) & 15;
        int rowl = (r & 3) + 8 * (r >> 2) + 4 * half;
        size_t base = (size_t)yb * rows_n + g * MBLK + w * 64 + rowl;
        part[base]      = fmaxf(vA, 0.0f);
        part[base + 32] = fmaxf(vB, 0.0f);
    }
}

// ---- Pass 2: min over sub-chunks per chunk, then mean ----
__global__ __launch_bounds__(256)
void pass2_kernel(const float* __restrict__ part2,
                  const float* __restrict__ part1, float* __restrict__ out,
                  int n1, int n2, int total2, int total1, float s2, float s1)
{
    __shared__ float wred[4];
    const int gpc = CHUNK / SUB;   // sub-chunks per chunk (2 at SUB=1024)
    const int n = total2 + total1;
    float s = 0.0f;
    for (int idx = blockIdx.x * 256 + threadIdx.x; idx < n;
         idx += gridDim.x * 256) {
        float m = FLT_MAX;
        if (idx < total2) {
            int cc  = idx / n1;
            int row = idx - cc * n1;
#pragma unroll
            for (int t = 0; t < gpc; ++t)
                m = fminf(m, part2[(size_t)(cc * gpc + t) * n1 + row]);
            s += fmaxf(m, 0.0f) * s2;
        } else {
            int i1  = idx - total2;
            int c1  = i1 / n2;
            int col = i1 - c1 * n2;
#pragma unroll
            for (int t = 0; t < gpc; ++t)
                m = fminf(m, part1[(size_t)(c1 * gpc + t) * n2 + col]);
            s += fmaxf(m, 0.0f) * s1;
        }
    }
#pragma unroll
    for (int off = 32; off > 0; off >>= 1) s += __shfl_down(s, off);
    const int lane = threadIdx.x & 63, w = threadIdx.x >> 6;
    if (lane == 0) wred[w] = s;
    __syncthreads();
    if (threadIdx.x == 0)
        atomicAdd(out, wred[0] + wred[1] + wred[2] + wred[3]);
}

// ---- Fallback (ws too small / odd shapes): R1's verified pure-VALU kernel ----
#define FB_RPT  2
#define FB_TILE (256 * FB_RPT)
__global__ __launch_bounds__(256, 2)
void chamfer_valu(const float* __restrict__ p1, const float* __restrict__ p2,
                  int n1, int n2, float* __restrict__ out)
{
    __shared__ float4 q[CHUNK];
    __shared__ float wsum[4];
    const int dir = blockIdx.z;
    const float* __restrict__ src = dir ? p2 : p1;
    const float* __restrict__ ref = dir ? p1 : p2;
    const int nsrc = dir ? n2 : n1;
    const int m    = dir ? n1 : n2;
    const int nchunks = nsrc / CHUNK;
    const int c = blockIdx.y;
    const int tile0 = blockIdx.x * FB_TILE;
    if (c >= nchunks || tile0 >= m) return;
    const float scale = 1.0f / ((float)nchunks * (float)m);
    const float* __restrict__ chunk = src + (size_t)c * CHUNK * 3;
    for (int k = threadIdx.x; k < CHUNK; k += 256) {
        float x = chunk[3*k], y = chunk[3*k+1], z = chunk[3*k+2];
        q[k] = make_float4(x, y, z, fmaf(x, x, fmaf(y, y, z * z)));
    }
    __syncthreads();
    float px[FB_RPT], py[FB_RPT], pz[FB_RPT], sp[FB_RPT], mna[FB_RPT], mnb[FB_RPT];
    bool valid[FB_RPT];
#pragma unroll
    for (int r = 0; r < FB_RPT; ++r) {
        int j = tile0 + threadIdx.x + r * 256;
        valid[r] = (j < m);
        int jj = valid[r] ? j : 0;
        float x = ref[3*jj], y = ref[3*jj+1], z = ref[3*jj+2];
        px[r] = -2.0f*x; py[r] = -2.0f*y; pz[r] = -2.0f*z;
        sp[r] = fmaf(x, x, fmaf(y, y, z * z));
        mna[r] = FLT_MAX; mnb[r] = FLT_MAX;
    }
#pragma unroll 2
    for (int k = 0; k < CHUNK; k += 2) {
        float4 qa = q[k], qb = q[k+1];
#pragma unroll
        for (int r = 0; r < FB_RPT; ++r) {
            mna[r] = fminf(mna[r], fmaf(px[r], qa.x, fmaf(py[r], qa.y, fmaf(pz[r], qa.z, qa.w))));
            mnb[r] = fminf(mnb[r], fmaf(px[r], qb.x, fmaf(py[r], qb.y, fmaf(pz[r], qb.z, qb.w))));
        }
    }
    float sum = 0.0f;
#pragma unroll
    for (int r = 0; r < FB_RPT; ++r)
        if (valid[r]) sum += fmaxf(fminf(mna[r], mnb[r]) + sp[r], 0.0f);
#pragma unroll
    for (int off = 32; off > 0; off >>= 1) sum += __shfl_down(sum, off);
    if ((threadIdx.x & 63) == 0) wsum[threadIdx.x >> 6] = sum;
    __syncthreads();
    if (threadIdx.x == 0)
        atomicAdd(out, (wsum[0]+wsum[1]+wsum[2]+wsum[3]) * scale);
}

extern "C" void kernel_launch(void* const* d_in, const int* in_sizes, int n_in,
                              void* d_out, int out_size, void* d_ws, size_t ws_size,
                              hipStream_t stream)
{
    const float* p1 = (const float*)d_in[0];  // output_pc [N,3]
    const float* p2 = (const float*)d_in[1];  // gt_pc     [M,3]
    float* out = (float*)d_out;
    const int n1 = in_sizes[0] / 3;
    const int n2 = in_sizes[1] / 3;

    const int nc1 = n1 / CHUNK, nc2 = n2 / CHUNK;
    const int nyb2 = n2 / SUB;            // p2 col sub-chunks (dir0)
    const int nyb1 = n1 / SUB;            // p1 col sub-chunks (dir1)

    unsigned short* Arec = (unsigned short*)d_ws;            // n1*32 B
    unsigned short* Brec = Arec + (size_t)n1 * 16;           // n2*32 B
    float* part2 = (float*)(Brec + (size_t)n2 * 16);         // nyb2*n1*4 B
    float* part1 = part2 + (size_t)nyb2 * n1;                // nyb1*n2*4 B
    const size_t need = (size_t)n1 * 32 + (size_t)n2 * 32 +
                        ((size_t)nyb2 * n1 + (size_t)nyb1 * n2) * 4;

    const bool shapes_ok = (n1 % CHUNK == 0) && (n2 % CHUNK == 0) &&
                           (n1 % MBLK == 0) && (n2 % MBLK == 0) &&
                           (n1 % SUB == 0) && (n2 % SUB == 0);

    if (shapes_ok && ws_size >= need) {
        pack_kernel<<<(n1 + n2 + 255) / 256, 256, 0, stream>>>(
            p1, p2, n1, n2, Arec, Brec);
        const int gx = max(n1, n2) / MBLK;
        const int gy = max(n1, n2) / SUB;
        dim3 grid(gx, gy, 2);
        chamfer_mfma<<<grid, 256, 0, stream>>>(Arec, Brec, part2, part1, n1, n2);
        const int total2 = nc2 * n1, total1 = nc1 * n2;
        pass2_kernel<<<512, 256, 0, stream>>>(
            part2, part1, out, n1, n2, total2, total1,
            1.0f / ((float)nc2 * (float)n1), 1.0f / ((float)nc1 * (float)n2));
    } else {
        const int t1 = (n2 + FB_TILE - 1) / FB_TILE;
        const int t2 = (n1 + FB_TILE - 1) / FB_TILE;
        dim3 grid(max(t1, t2), max(nc1, nc2), 2);
        chamfer_valu<<<grid, 256, 0, stream>>>(p1, p2, n1, n2, out);
    }
}

// Round 13
// 87.231 us; speedup vs baseline: 1.1324x; 1.1324x over previous
//
#include <hip/hip_runtime.h>
#include <float.h>

#define CHUNK 2048
#define SUB   2048   // cols per block = full chunk (R11-best: one resident cohort)
#define MBLK  128    // rows per block = 4 waves x one 32-row strip

typedef __attribute__((ext_vector_type(8)))  short short8;
typedef __attribute__((ext_vector_type(16))) float f32x16;

// ---- bf16 split helpers (RN-even; inputs finite) ----
static __device__ __forceinline__ unsigned short f2bf(float f) {
    unsigned u = __float_as_uint(f);
    return (unsigned short)((u + 0x7FFFu + ((u >> 16) & 1u)) >> 16);
}
static __device__ __forceinline__ float bf2f(unsigned short s) {
    return __uint_as_float(((unsigned)s) << 16);
}

// ---- Pass 0: pack K=16 bf16 records ----
// A-record (p1 point):  [ph(3), pl(3), ph(3), pl(3), sp_hi, sp_lo, 1, 1]
// B-record (p2 point):  [uh(3), uh(3), ul(3), ul(3), 1, 1, sq_hi, sq_lo]
// Mutually transposable; dot(A_k,B_k) = sp + sq - 2 p.q with either side as
// the MFMA A-operand. Verified R5-R12 (absmax 0) in both orientations.
__global__ void pack_kernel(const float* __restrict__ p1,
                            const float* __restrict__ p2, int n1, int n2,
                            unsigned short* __restrict__ Arec,
                            unsigned short* __restrict__ Brec)
{
    int i = blockIdx.x * blockDim.x + threadIdx.x;
    if (i >= n1 + n2) return;
    const bool isA = (i < n1);
    const float* s = isA ? p1 : p2;
    const int j = isA ? i : i - n1;
    float x = s[3 * j + 0], y = s[3 * j + 1], z = s[3 * j + 2];

    unsigned short r[16];
    if (isA) {
        unsigned short hx = f2bf(x), hy = f2bf(y), hz = f2bf(z);
        unsigned short lx = f2bf(x - bf2f(hx)), ly = f2bf(y - bf2f(hy)),
                       lz = f2bf(z - bf2f(hz));
        float sp = fmaf(x, x, fmaf(y, y, z * z));
        unsigned short sh = f2bf(sp), sl = f2bf(sp - bf2f(sh));
        r[0]=hx; r[1]=hy; r[2]=hz;  r[3]=lx; r[4]=ly; r[5]=lz;
        r[6]=hx; r[7]=hy; r[8]=hz;  r[9]=lx; r[10]=ly; r[11]=lz;
        r[12]=sh; r[13]=sl; r[14]=0x3F80; r[15]=0x3F80;
        unsigned short* dst = Arec + (size_t)j * 16;
#pragma unroll
        for (int t = 0; t < 16; ++t) dst[t] = r[t];
    } else {
        float ux = -2.0f * x, uy = -2.0f * y, uz = -2.0f * z;
        unsigned short hx = f2bf(ux), hy = f2bf(uy), hz = f2bf(uz);
        unsigned short lx = f2bf(ux - bf2f(hx)), ly = f2bf(uy - bf2f(hy)),
                       lz = f2bf(uz - bf2f(hz));
        float sq = fmaf(x, x, fmaf(y, y, z * z));
        unsigned short sh = f2bf(sq), sl = f2bf(sq - bf2f(sh));
        r[0]=hx; r[1]=hy; r[2]=hz;  r[3]=hx; r[4]=hy; r[5]=hz;
        r[6]=lx; r[7]=ly; r[8]=lz;  r[9]=lx; r[10]=ly; r[11]=lz;
        r[12]=0x3F80; r[13]=0x3F80; r[14]=sh; r[15]=sl;
        unsigned short* dst = Brec + (size_t)j * 16;
#pragma unroll
        for (int t = 0; t < 16; ++t) dst[t] = r[t];
    }
}

// ---- rowmin tournament across 32 lanes (verified R6-R12, absmax 0) ----
static __device__ __forceinline__ float tourney16(float rm[16], int l31)
{
#pragma unroll
    for (int r = 0; r < 8; ++r) {
        float lo = fminf(rm[r],     __shfl_xor(rm[r],     16));
        float hi = fminf(rm[r + 8], __shfl_xor(rm[r + 8], 16));
        rm[r] = (l31 & 16) ? hi : lo;
    }
#pragma unroll
    for (int r = 0; r < 4; ++r) {
        float lo = fminf(rm[r],     __shfl_xor(rm[r],     8));
        float hi = fminf(rm[r + 4], __shfl_xor(rm[r + 4], 8));
        rm[r] = (l31 & 8) ? hi : lo;
    }
#pragma unroll
    for (int r = 0; r < 2; ++r) {
        float lo = fminf(rm[r],     __shfl_xor(rm[r],     4));
        float hi = fminf(rm[r + 2], __shfl_xor(rm[r + 2], 4));
        rm[r] = (l31 & 4) ? hi : lo;
    }
    {
        float lo = fminf(rm[0], __shfl_xor(rm[0], 2));
        float hi = fminf(rm[1], __shfl_xor(rm[1], 2));
        rm[0] = (l31 & 2) ? hi : lo;
    }
    return fminf(rm[0], __shfl_xor(rm[0], 1));
}

// ---- Pass 1: pure-rowmin MFMA kernel, both directions via blockIdx.z ----
// R13 = exact R11 configuration (measured best: bench 88.4 us).
// Evidence ledger across R5-R12: the only lever that moved this kernel is
// resident-wave count (8 waves/SIMD, full-CU single cohort = this shape).
// Falsified: 2x-work single-pass (R5), LDS/global atomics (R5/R6), plain
// stores (R7), prefetch depth 1/2 (R8/R10), cohort turnover (R11 partial,
// +3 us), load-count/TLP trades (R9, R12). Remaining wall ~30 us vs ~9 us
// issue floor is latency-bound residue no source-level structure reached.
// v_mfma_f32_32x32x16_bf16: A[m=lane&31][k=half*8+j], B[k=half*8+j][n=lane&31],
//   C/D: col=lane&31, row=(reg&3)+8*(reg>>2)+4*half.
__global__ __launch_bounds__(256, 8)
void chamfer_mfma(const unsigned short* __restrict__ Arec,
                  const unsigned short* __restrict__ Brec,
                  float* __restrict__ part2, float* __restrict__ part1,
                  int n1, int n2)
{
    const int dir = blockIdx.z;
    const unsigned short* __restrict__ Ap = dir ? Brec : Arec;
    const unsigned short* __restrict__ Bp = dir ? Arec : Brec;
    float* __restrict__ part = dir ? part1 : part2;
    const int rows_n = dir ? n2 : n1;
    const int cols_n = dir ? n1 : n2;

    const int tid  = threadIdx.x;
    const int g    = blockIdx.x;          // row group (128 rows of A-side)
    const int yb   = blockIdx.y;          // col chunk (2048 cols of B-side)
    if (g * MBLK >= rows_n || yb * SUB >= cols_n) return;  // uniform

    const int lane = tid & 63;
    const int w    = tid >> 6;
    const int half = lane >> 5;
    const int l31  = lane & 31;

    // A fragment (fixed per wave): one 32-row strip
    const int rA = g * MBLK + w * 32 + l31;
    short8 aA = *(const short8*)(Ap + (size_t)rA * 16 + half * 8);

    const unsigned short* bp =
        Bp + (size_t)(yb * SUB + l31) * 16 + half * 8;

    const f32x16 z16 = {0,0,0,0, 0,0,0,0, 0,0,0,0, 0,0,0,0};
    float rm[16];
#pragma unroll
    for (int r = 0; r < 16; ++r) rm[r] = FLT_MAX;

    const int NT = SUB / 32;   // 64 tiles
    for (int t = 0; t < NT; ++t) {
        short8 b = *(const short8*)(bp + (size_t)t * 512);
        f32x16 d = __builtin_amdgcn_mfma_f32_32x32x16_bf16(aA, b, z16, 0, 0, 0);
#pragma unroll
        for (int r = 0; r < 16; ++r) rm[r] = fminf(rm[r], d[r]);
    }

    // ---- tournament, one plain store per even lane ----
    float v = tourney16(rm, l31);
    if ((l31 & 1) == 0) {
        int r = (l31 >> 1) & 15;
        int rowl = (r & 3) + 8 * (r >> 2) + 4 * half;
        int grow = g * MBLK + w * 32 + rowl;
        part[(size_t)yb * rows_n + grow] = fmaxf(v, 0.0f);
    }
}

// ---- Pass 2: min over sub-chunks per chunk, then mean ----
__global__ __launch_bounds__(256)
void pass2_kernel(const float* __restrict__ part2,
                  const float* __restrict__ part1, float* __restrict__ out,
                  int n1, int n2, int total2, int total1, float s2, float s1)
{
    __shared__ float wred[4];
    const int gpc = CHUNK / SUB;   // sub-chunks per chunk (1 at SUB=2048)
    const int n = total2 + total1;
    float s = 0.0f;
    for (int idx = blockIdx.x * 256 + threadIdx.x; idx < n;
         idx += gridDim.x * 256) {
        float m = FLT_MAX;
        if (idx < total2) {
            int cc  = idx / n1;
            int row = idx - cc * n1;
#pragma unroll
            for (int t = 0; t < gpc; ++t)
                m = fminf(m, part2[(size_t)(cc * gpc + t) * n1 + row]);
            s += fmaxf(m, 0.0f) * s2;
        } else {
            int i1  = idx - total2;
            int c1  = i1 / n2;
            int col = i1 - c1 * n2;
#pragma unroll
            for (int t = 0; t < gpc; ++t)
                m = fminf(m, part1[(size_t)(c1 * gpc + t) * n2 + col]);
            s += fmaxf(m, 0.0f) * s1;
        }
    }
#pragma unroll
    for (int off = 32; off > 0; off >>= 1) s += __shfl_down(s, off);
    const int lane = threadIdx.x & 63, w = threadIdx.x >> 6;
    if (lane == 0) wred[w] = s;
    __syncthreads();
    if (threadIdx.x == 0)
        atomicAdd(out, wred[0] + wred[1] + wred[2] + wred[3]);
}

// ---- Fallback (ws too small / odd shapes): R1's verified pure-VALU kernel ----
#define FB_RPT  2
#define FB_TILE (256 * FB_RPT)
__global__ __launch_bounds__(256, 2)
void chamfer_valu(const float* __restrict__ p1, const float* __restrict__ p2,
                  int n1, int n2, float* __restrict__ out)
{
    __shared__ float4 q[CHUNK];
    __shared__ float wsum[4];
    const int dir = blockIdx.z;
    const float* __restrict__ src = dir ? p2 : p1;
    const float* __restrict__ ref = dir ? p1 : p2;
    const int nsrc = dir ? n2 : n1;
    const int m    = dir ? n1 : n2;
    const int nchunks = nsrc / CHUNK;
    const int c = blockIdx.y;
    const int tile0 = blockIdx.x * FB_TILE;
    if (c >= nchunks || tile0 >= m) return;
    const float scale = 1.0f / ((float)nchunks * (float)m);
    const float* __restrict__ chunk = src + (size_t)c * CHUNK * 3;
    for (int k = threadIdx.x; k < CHUNK; k += 256) {
        float x = chunk[3*k], y = chunk[3*k+1], z = chunk[3*k+2];
        q[k] = make_float4(x, y, z, fmaf(x, x, fmaf(y, y, z * z)));
    }
    __syncthreads();
    float px[FB_RPT], py[FB_RPT], pz[FB_RPT], sp[FB_RPT], mna[FB_RPT], mnb[FB_RPT];
    bool valid[FB_RPT];
#pragma unroll
    for (int r = 0; r < FB_RPT; ++r) {
        int j = tile0 + threadIdx.x + r * 256;
        valid[r] = (j < m);
        int jj = valid[r] ? j : 0;
        float x = ref[3*jj], y = ref[3*jj+1], z = ref[3*jj+2];
        px[r] = -2.0f*x; py[r] = -2.0f*y; pz[r] = -2.0f*z;
        sp[r] = fmaf(x, x, fmaf(y, y, z * z));
        mna[r] = FLT_MAX; mnb[r] = FLT_MAX;
    }
#pragma unroll 2
    for (int k = 0; k < CHUNK; k += 2) {
        float4 qa = q[k], qb = q[k+1];
#pragma unroll
        for (int r = 0; r < FB_RPT; ++r) {
            mna[r] = fminf(mna[r], fmaf(px[r], qa.x, fmaf(py[r], qa.y, fmaf(pz[r], qa.z, qa.w))));
            mnb[r] = fminf(mnb[r], fmaf(px[r], qb.x, fmaf(py[r], qb.y, fmaf(pz[r], qb.z, qb.w))));
        }
    }
    float sum = 0.0f;
#pragma unroll
    for (int r = 0; r < FB_RPT; ++r)
        if (valid[r]) sum += fmaxf(fminf(mna[r], mnb[r]) + sp[r], 0.0f);
#pragma unroll
    for (int off = 32; off > 0; off >>= 1) sum += __shfl_down(sum, off);
    if ((threadIdx.x & 63) == 0) wsum[threadIdx.x >> 6] = sum;
    __syncthreads();
    if (threadIdx.x == 0)
        atomicAdd(out, (wsum[0]+wsum[1]+wsum[2]+wsum[3]) * scale);
}

extern "C" void kernel_launch(void* const* d_in, const int* in_sizes, int n_in,
                              void* d_out, int out_size, void* d_ws, size_t ws_size,
                              hipStream_t stream)
{
    const float* p1 = (const float*)d_in[0];  // output_pc [N,3]
    const float* p2 = (const float*)d_in[1];  // gt_pc     [M,3]
    float* out = (float*)d_out;
    const int n1 = in_sizes[0] / 3;
    const int n2 = in_sizes[1] / 3;

    const int nc1 = n1 / CHUNK, nc2 = n2 / CHUNK;
    const int nyb2 = n2 / SUB;            // p2 col chunks (dir0)
    const int nyb1 = n1 / SUB;            // p1 col chunks (dir1)

    unsigned short* Arec = (unsigned short*)d_ws;            // n1*32 B
    unsigned short* Brec = Arec + (size_t)n1 * 16;           // n2*32 B
    float* part2 = (float*)(Brec + (size_t)n2 * 16);         // nyb2*n1*4 B
    float* part1 = part2 + (size_t)nyb2 * n1;                // nyb1*n2*4 B
    const size_t need = (size_t)n1 * 32 + (size_t)n2 * 32 +
                        ((size_t)nyb2 * n1 + (size_t)nyb1 * n2) * 4;

    const bool shapes_ok = (n1 % CHUNK == 0) && (n2 % CHUNK == 0) &&
                           (n1 % MBLK == 0) && (n2 % MBLK == 0) &&
                           (n1 % SUB == 0) && (n2 % SUB == 0);

    if (shapes_ok && ws_size >= need) {
        pack_kernel<<<(n1 + n2 + 255) / 256, 256, 0, stream>>>(
            p1, p2, n1, n2, Arec, Brec);
        const int gx = max(n1, n2) / MBLK;
        const int gy = max(n1, n2) / SUB;
        dim3 grid(gx, gy, 2);
        chamfer_mfma<<<grid, 256, 0, stream>>>(Arec, Brec, part2, part1, n1, n2);
        const int total2 = nc2 * n1, total1 = nc1 * n2;
        pass2_kernel<<<512, 256, 0, stream>>>(
            part2, part1, out, n1, n2, total2, total1,
            1.0f / ((float)nc2 * (float)n1), 1.0f / ((float)nc1 * (float)n2));
    } else {
        const int t1 = (n2 + FB_TILE - 1) / FB_TILE;
        const int t2 = (n1 + FB_TILE - 1) / FB_TILE;
        dim3 grid(max(t1, t2), max(nc1, nc2), 2);
        chamfer_valu<<<grid, 256, 0, stream>>>(p1, p2, n1, n2, out);
    }
}